// Round 7
// baseline (2100.329 us; speedup 1.0000x reference)
//
#include <hip/hip_runtime.h>
#include <hip/hip_bf16.h>
#include <math.h>

#define KNN 20
constexpr int NPTS = 2048;   // N
constexpr int NBAT = 8;      // B
constexpr int M_TOT = NBAT * NPTS;  // 16384

// ---------------------------------------------------------------- sq norms
__global__ __launch_bounds__(256) void sqnorm_kernel(const float* __restrict__ X, int lda, int C,
                                                     float* __restrict__ sq) {
  int i = blockIdx.x * 256 + threadIdx.x;
  if (i >= M_TOT) return;
  const float* p = X + (size_t)i * lda;
  float s = 0.f;
  for (int c = 0; c < C; ++c) { float v = p[c]; s = fmaf(v, v, s); }
  sq[i] = s;
}

// ---------------------------------------------------------------- top-20 sorted insert (swap chain)
#define INSERT_CAND(key_, j_)                                  \
  if ((key_) < dl[KNN - 1]) {                                  \
    float _k = (key_); int _j = (j_);                          \
    _Pragma("unroll")                                          \
    for (int p = 0; p < KNN; ++p) {                            \
      bool sw = _k < dl[p];                                    \
      float od = dl[p]; int oi = il[p];                        \
      dl[p] = sw ? _k : od; il[p] = sw ? _j : oi;              \
      _k = sw ? od : _k; _j = sw ? oi : _j;                    \
    }                                                          \
  }

// ---------------------------------------------------------------- kNN v6
// v5 main loop (32 rows x 64 cands/chunk, 8 select lanes/row, swizzled dist,
// 22.1KB LDS) with NO in-kernel merge at all: each lane writes its private
// sorted top-20 straight to global (32 lists/row; idx as u16 to fit 63MB in
// the dead uv region). Exact 32-way lex merge happens in knnmerge_kernel.
// No merge code -> VGPR back to ~64 (v3 proved the loop fits) -> 7 blocks/CU.
template <int C, int CSPLIT>
__global__ __launch_bounds__(256, 8) void knn6_kernel(const float* __restrict__ X, int lda,
                                                      const float* __restrict__ sq,
                                                      float* __restrict__ pd,
                                                      unsigned short* __restrict__ pi) {
  constexpr int ROWS = 32, CHK = 64, KB = 32, SEL = 8;
  constexpr int KP = KB + 4;                  // staging stride (f4-aligned, padded)
  constexpr int DP = CHK + 1;                 // 65 (odd): select reads 2-way
  constexpr int NKB = (C == 3) ? 1 : C / KB;
  constexpr int XI_W = (C == 3) ? 4 : KP;
  constexpr int SMF = ROWS * XI_W + CHK * XI_W + ROWS * DP;
  __shared__ __align__(16) float smem[SMF];
  float* xi = smem;                                    // [ROWS][XI_W]
  float* xj = smem + ROWS * XI_W;                      // [CHK][XI_W]
  float* dist = smem + (ROWS + CHK) * XI_W;            // [ROWS][DP] (col-swizzled)

  const int b = blockIdx.z;
  const int m0 = blockIdx.x * ROWS;
  const int jsplit = blockIdx.y * (NPTS / CSPLIT);
  const int t = threadIdx.x;
  const int tx = t & 15, ty = t >> 4;         // compute roles: rows ty+16i, cols tx+16j
  const int sr = t >> 3, ss = t & 7;          // select roles: row sr, col-slice ss
  const float* Xb = X + (size_t)b * NPTS * lda;
  const float* sqb = sq + b * NPTS;

  float dl[KNN]; int il[KNN];
#pragma unroll
  for (int p = 0; p < KNN; ++p) { dl[p] = INFINITY; il[p] = 0x7fffffff; }

  for (int c0 = 0; c0 < NPTS / CSPLIT; c0 += CHK) {
    const int jb = jsplit + c0;
    float acc[2][4] = {};

    if constexpr (C == 3) {
      __syncthreads();
      // full-coverage grid-stride staging (96 + 192 elements, 256 threads)
      for (int e = t; e < ROWS * 3; e += 256) {
        int rr = e / 3, cc = e % 3;
        xi[rr * 4 + cc] = Xb[(size_t)(m0 + rr) * lda + cc];
      }
      for (int e = t; e < CHK * 3; e += 256) {
        int rr = e / 3, cc = e % 3;
        xj[rr * 4 + cc] = Xb[(size_t)(jb + rr) * lda + cc];
      }
      __syncthreads();
#pragma unroll
      for (int i = 0; i < 2; ++i) {
        const float* xr = xi + (ty + 16 * i) * 4;
        float x0 = xr[0], x1 = xr[1], x2 = xr[2];
#pragma unroll
        for (int j = 0; j < 4; ++j) {
          const float* xc = xj + (tx + 16 * j) * 4;
          acc[i][j] = fmaf(x0, xc[0], fmaf(x1, xc[1], x2 * xc[2]));
        }
      }
    } else {
#pragma unroll
      for (int kb = 0; kb < NKB; ++kb) {
        __syncthreads();
        // stage xi 32x32 (256 f4) + xj 64x32 (512 f4): 3 f4 per thread
#pragma unroll
        for (int q = 0; q < 3; ++q) {
          if (q == 0) {
            int rr = t >> 3, cc = t & 7;
            *(float4*)(xi + rr * KP + cc * 4) =
                *(const float4*)(Xb + (size_t)(m0 + rr) * lda + kb * KB + cc * 4);
          } else {
            int f = t + (q - 1) * 256;
            int rr = f >> 3, cc = f & 7;
            *(float4*)(xj + rr * KP + cc * 4) =
                *(const float4*)(Xb + (size_t)(jb + rr) * lda + kb * KB + cc * 4);
          }
        }
        __syncthreads();
#pragma unroll
        for (int k4 = 0; k4 < KB / 4; ++k4) {
          float4 av[2], bv[4];
#pragma unroll
          for (int i = 0; i < 2; ++i) av[i] = *(const float4*)(xi + (ty + 16 * i) * KP + k4 * 4);
#pragma unroll
          for (int j = 0; j < 4; ++j) bv[j] = *(const float4*)(xj + (tx + 16 * j) * KP + k4 * 4);
#pragma unroll
          for (int i = 0; i < 2; ++i)
#pragma unroll
            for (int j = 0; j < 4; ++j) {
              acc[i][j] = fmaf(av[i].x, bv[j].x, acc[i][j]);
              acc[i][j] = fmaf(av[i].y, bv[j].y, acc[i][j]);
              acc[i][j] = fmaf(av[i].z, bv[j].z, acc[i][j]);
              acc[i][j] = fmaf(av[i].w, bv[j].w, acc[i][j]);
            }
        }
      }
    }

    // ranking key: sq_j - 2*dot (same fma order as v3/v5 -> bit-identical keys).
    // dist col swizzled: col' = col ^ ((row&1)<<4)  (write 2-way, read 2-way)
    float sqv[4];
#pragma unroll
    for (int j = 0; j < 4; ++j) sqv[j] = sqb[jb + tx + 16 * j];
#pragma unroll
    for (int i = 0; i < 2; ++i) {
      const int row = ty + 16 * i;
      const int sw = (row & 1) << 4;
#pragma unroll
      for (int j = 0; j < 4; ++j)
        dist[row * DP + ((tx + 16 * j) ^ sw)] = fmaf(-2.f, acc[i][j], sqv[j]);
    }
    __syncthreads();

    // select: 8 lanes/row, each scans 8 cands (ascending j within lane)
    {
      const int sw = (sr & 1) << 4;
#pragma unroll
      for (int q = 0; q < 8; ++q) {
        float key = dist[sr * DP + ((ss * 8 + q) ^ sw)];
        int jidx = jb + ss * 8 + q;
        INSERT_CAND(key, jidx)
      }
    }
  }

  // ---- direct per-lane global write: list g of row (sorted top-20)
  const size_t rowg = (size_t)(b * NPTS + m0 + sr);
  const int g = blockIdx.y * SEL + ss;
  float* od = pd + (rowg * (CSPLIT * SEL) + g) * KNN;
  unsigned short* oi = pi + (rowg * (CSPLIT * SEL) + g) * KNN;
#pragma unroll
  for (int p = 0; p < KNN; ++p) {
    od[p] = dl[p];
    oi[p] = (unsigned short)(il[p] & 0xFFFF);   // sentinel 0x7fffffff -> 0xFFFF (d=INF, never wins)
  }
}

// ---------------------------------------------------------------- exact NL-way merge of sorted lists
template <int NL>
__global__ __launch_bounds__(64) void knnmerge_kernel(const float* __restrict__ pd,
                                                      const unsigned short* __restrict__ pi,
                                                      int* __restrict__ knn_out) {
  int row = blockIdx.x * 64 + threadIdx.x;
  if (row >= M_TOT) return;
  const float* d = pd + (size_t)row * NL * KNN;
  const unsigned short* ii = pi + (size_t)row * NL * KNN;
  int p[NL];
#pragma unroll
  for (int g = 0; g < NL; ++g) p[g] = 0;
  int* orow = knn_out + (size_t)row * KNN;
  for (int k = 0; k < KNN; ++k) {
    float bd = INFINITY; int bi = 0x7fffffff; int bg = 0;
#pragma unroll
    for (int g = 0; g < NL; ++g) {
      float dd = d[g * KNN + p[g]];
      int iv = (int)ii[g * KNN + p[g]];
      if (dd < bd || (dd == bd && iv < bi)) { bd = dd; bi = iv; bg = g; }
    }
    orow[k] = bi;
#pragma unroll
    for (int g = 0; g < NL; ++g) p[g] += (bg == g) ? 1 : 0;   // static-index update
  }
}

// ---------------------------------------------------------------- weight prep: [Wd ; Wc-Wd]
__global__ __launch_bounds__(256) void wcat_kernel(const float* __restrict__ W, int O, int Cc,
                                                   float* __restrict__ out) {
  int i = blockIdx.x * 256 + threadIdx.x;
  if (i >= O * Cc) return;
  int o = i / Cc, c = i % Cc;
  float wd = W[(size_t)o * 2 * Cc + c];
  float wc = W[(size_t)o * 2 * Cc + Cc + c];
  out[(size_t)o * Cc + c] = wd;              // rows 0..O-1   : v = Wd * x
  out[(size_t)(O + o) * Cc + c] = wc - wd;   // rows O..2O-1  : u = (Wc-Wd) * x
}

// ---------------------------------------------------------------- fp32 tiled GEMM
// out[M, NO] = A[M, K](lda) @ Wt[NO, K]^T ;  BM=BN=64, BK=16, 256 thr, 4x4 micro-tile
template <bool FUSE>
__global__ __launch_bounds__(256) void gemm_kernel(const float* __restrict__ A, int lda, int K,
                                                   const float* __restrict__ Wt, int NO,
                                                   float* __restrict__ out,
                                                   const float* __restrict__ bn) {
  __shared__ float As[16][68];
  __shared__ float Bs[16][68];
  const int t = threadIdx.x;
  const int tx = t & 15, ty = t >> 4;
  const int m0 = blockIdx.x * 64, n0 = blockIdx.y * 64;
  float acc[4][4] = {};

  for (int k0 = 0; k0 < K; k0 += 16) {
#pragma unroll
    for (int q = 0; q < 4; ++q) {
      int e = t + q * 256;
      int rr = e >> 4, cc = e & 15;
      int kk = k0 + cc;
      As[cc][rr] = (kk < K) ? A[(size_t)(m0 + rr) * lda + kk] : 0.f;
      Bs[cc][rr] = (kk < K) ? Wt[(size_t)(n0 + rr) * K + kk] : 0.f;
    }
    __syncthreads();
#pragma unroll
    for (int kk = 0; kk < 16; ++kk) {
      float4 av = *(const float4*)(&As[kk][ty * 4]);
      float4 bv = *(const float4*)(&Bs[kk][tx * 4]);
      float a[4] = {av.x, av.y, av.z, av.w};
      float bb[4] = {bv.x, bv.y, bv.z, bv.w};
#pragma unroll
      for (int i = 0; i < 4; ++i)
#pragma unroll
        for (int j = 0; j < 4; ++j) acc[i][j] = fmaf(a[i], bb[j], acc[i][j]);
    }
    __syncthreads();
  }

#pragma unroll
  for (int i = 0; i < 4; ++i) {
    int row = m0 + ty * 4 + i;
#pragma unroll
    for (int j = 0; j < 4; ++j) {
      int col = n0 + tx * 4 + j;
      float v = acc[i][j];
      if constexpr (FUSE) {
        float g = bn[col], be = bn[NO + col], mm = bn[2 * NO + col], va = bn[3 * NO + col];
        float s = g * rsqrtf(va + 1e-5f);
        v = fmaf(s, v - mm, be);
        v = v > 0.f ? v : 0.2f * v;
      }
      out[(size_t)row * NO + col] = v;
    }
  }
}

// ---------------------------------------------------------------- gather + k-max + BN + lrelu
__global__ void gathermax_kernel(const float* __restrict__ uv, const int* __restrict__ knn_in,
                                 const float* __restrict__ bn, int O,
                                 float* __restrict__ outc, int ldo) {
  const int n = blockIdx.x;   // global row b*N + n
  const int o = threadIdx.x;
  __shared__ int js[KNN];
  if (o < KNN) js[o] = knn_in[(size_t)n * KNN + o];
  __syncthreads();
  const int b = n >> 11;
  const int ld2 = 2 * O;
  const float* uvb = uv + (size_t)b * NPTS * ld2;
  float m = -INFINITY;
#pragma unroll
  for (int k = 0; k < KNN; ++k) m = fmaxf(m, uvb[(size_t)js[k] * ld2 + o]);
  float u = uv[(size_t)n * ld2 + O + o];
  float g = bn[o], be = bn[O + o], mm = bn[2 * O + o], va = bn[3 * O + o];
  float s = g * rsqrtf(va + 1e-5f);
  float y = fmaf(s, m + u - mm, be);
  y = y > 0.f ? y : 0.2f * y;
  outc[(size_t)n * ldo + o] = y;
}

// ---------------------------------------------------------------- final global max+avg reduce
__global__ __launch_bounds__(256) void reduce1_kernel(const float* __restrict__ feat,
                                                      float* __restrict__ part) {
  const int sp = blockIdx.x;                 // 16 splits of 128 rows
  const int b = blockIdx.z;
  const int o = blockIdx.y * 256 + threadIdx.x;
  const float* f = feat + ((size_t)b * NPTS + sp * 128) * 1024 + o;
  float mx = -INFINITY, sm = 0.f;
  for (int n = 0; n < 128; ++n) { float v = f[(size_t)n * 1024]; mx = fmaxf(mx, v); sm += v; }
  part[((size_t)(b * 16 + sp)) * 1024 + o] = mx;
  part[131072 + ((size_t)(b * 16 + sp)) * 1024 + o] = sm;
}

__global__ __launch_bounds__(256) void reduce2_kernel(const float* __restrict__ part,
                                                      float* __restrict__ out) {
  const int b = blockIdx.y;
  const int o = blockIdx.x * 256 + threadIdx.x;
  float mx = -INFINITY, sm = 0.f;
  for (int sp = 0; sp < 16; ++sp) {
    mx = fmaxf(mx, part[((size_t)(b * 16 + sp)) * 1024 + o]);
    sm += part[131072 + ((size_t)(b * 16 + sp)) * 1024 + o];
  }
  out[(size_t)b * 2048 + o] = mx;
  out[(size_t)b * 2048 + 1024 + o] = sm * (1.f / 2048.f);
}

// ---------------------------------------------------------------- launch
extern "C" void kernel_launch(void* const* d_in, const int* in_sizes, int n_in,
                              void* d_out, int out_size, void* d_ws, size_t ws_size,
                              hipStream_t stream) {
  const float* x   = (const float*)d_in[0];
  const float* W1  = (const float*)d_in[1];
  const float* W2  = (const float*)d_in[2];
  const float* W3  = (const float*)d_in[3];
  const float* W4  = (const float*)d_in[4];
  const float* W5  = (const float*)d_in[5];
  const float* bn1 = (const float*)d_in[6];
  const float* bn2 = (const float*)d_in[7];
  const float* bn3 = (const float*)d_in[8];
  const float* bn4 = (const float*)d_in[9];
  const float* bn5 = (const float*)d_in[10];
  float* out = (float*)d_out;

  char* ws = (char*)d_ws;
  float* xcat  = (float*)(ws);                 // 16384*512 f32 = 32 MiB
  float* uv    = (float*)(ws + 33554432);      // 16384*1024 f32 = 64 MiB (uv / feat)
  int*   knnb  = (int*)  (ws + 100663296);     // 16384*20 int  = 1.25 MiB
  float* sqb   = (float*)(ws + 101974016);     // 16384 f32
  float* wcat  = (float*)(ws + 102039552);     // <= 512*256 f32
  float* part  = (float*)(ws + 102563840);     // 2*8*16*1024 f32 = 1 MiB
  // kNN partial lists alias the (idle during kNN) uv region:
  // pd = 16384*32*20 f32 = 42MB, pi = same count u16 = 21MB; 63MB <= 64MiB
  float*          pd = uv;
  unsigned short* pi = (unsigned short*)(ws + 33554432 + 41943040);

  const dim3 kg(NPTS / 32, 4, NBAT);   // 2048 blocks

  // ---- Layer 1: x(B,N,3) -> x1(64) @ xcat col 0
  sqnorm_kernel<<<64, 256, 0, stream>>>(x, 3, 3, sqb);
  knn6_kernel<3, 4><<<kg, 256, 0, stream>>>(x, 3, sqb, pd, pi);
  knnmerge_kernel<32><<<256, 64, 0, stream>>>(pd, pi, knnb);
  wcat_kernel<<<1, 256, 0, stream>>>(W1, 64, 3, wcat);
  gemm_kernel<false><<<dim3(256, 2), 256, 0, stream>>>(x, 3, 3, wcat, 128, uv, nullptr);
  gathermax_kernel<<<16384, 64, 0, stream>>>(uv, knnb, bn1, 64, xcat + 0, 512);

  // ---- Layer 2: x1(64) -> x2(64) @ xcat col 64
  sqnorm_kernel<<<64, 256, 0, stream>>>(xcat, 512, 64, sqb);
  knn6_kernel<64, 4><<<kg, 256, 0, stream>>>(xcat, 512, sqb, pd, pi);
  knnmerge_kernel<32><<<256, 64, 0, stream>>>(pd, pi, knnb);
  wcat_kernel<<<16, 256, 0, stream>>>(W2, 64, 64, wcat);
  gemm_kernel<false><<<dim3(256, 2), 256, 0, stream>>>(xcat, 512, 64, wcat, 128, uv, nullptr);
  gathermax_kernel<<<16384, 64, 0, stream>>>(uv, knnb, bn2, 64, xcat + 64, 512);

  // ---- Layer 3: x2(64) -> x3(128) @ xcat col 128
  sqnorm_kernel<<<64, 256, 0, stream>>>(xcat + 64, 512, 64, sqb);
  knn6_kernel<64, 4><<<kg, 256, 0, stream>>>(xcat + 64, 512, sqb, pd, pi);
  knnmerge_kernel<32><<<256, 64, 0, stream>>>(pd, pi, knnb);
  wcat_kernel<<<32, 256, 0, stream>>>(W3, 128, 64, wcat);
  gemm_kernel<false><<<dim3(256, 4), 256, 0, stream>>>(xcat + 64, 512, 64, wcat, 256, uv, nullptr);
  gathermax_kernel<<<16384, 128, 0, stream>>>(uv, knnb, bn3, 128, xcat + 128, 512);

  // ---- Layer 4: x3(128) -> x4(256) @ xcat col 256
  sqnorm_kernel<<<64, 256, 0, stream>>>(xcat + 128, 512, 128, sqb);
  knn6_kernel<128, 4><<<kg, 256, 0, stream>>>(xcat + 128, 512, sqb, pd, pi);
  knnmerge_kernel<32><<<256, 64, 0, stream>>>(pd, pi, knnb);
  wcat_kernel<<<128, 256, 0, stream>>>(W4, 256, 128, wcat);
  gemm_kernel<false><<<dim3(256, 8), 256, 0, stream>>>(xcat + 128, 512, 128, wcat, 512, uv, nullptr);
  gathermax_kernel<<<16384, 256, 0, stream>>>(uv, knnb, bn4, 256, xcat + 256, 512);

  // ---- Final MLP: feat = lrelu(bn5(xcat @ W5^T))
  gemm_kernel<true><<<dim3(256, 16), 256, 0, stream>>>(xcat, 512, 512, W5, 1024, uv, bn5);

  // ---- global max + mean over N
  reduce1_kernel<<<dim3(16, 4, 8), 256, 0, stream>>>(uv, part);
  reduce2_kernel<<<dim3(4, 8), 256, 0, stream>>>(part, out);

  (void)in_sizes; (void)n_in; (void)out_size; (void)ws_size;
}

// Round 8
// 1475.852 us; speedup vs baseline: 1.4231x; 1.4231x over previous
//
#include <hip/hip_runtime.h>
#include <hip/hip_bf16.h>
#include <math.h>

#define KNN 20
constexpr int NPTS = 2048;   // N
constexpr int NBAT = 8;      // B
constexpr int M_TOT = NBAT * NPTS;  // 16384

// ---------------------------------------------------------------- sq norms
__global__ __launch_bounds__(256) void sqnorm_kernel(const float* __restrict__ X, int lda, int C,
                                                     float* __restrict__ sq) {
  int i = blockIdx.x * 256 + threadIdx.x;
  if (i >= M_TOT) return;
  const float* p = X + (size_t)i * lda;
  float s = 0.f;
  for (int c = 0; c < C; ++c) { float v = p[c]; s = fmaf(v, v, s); }
  sq[i] = s;
}

// ---------------------------------------------------------------- top-20 sorted insert (swap chain)
#define INSERT_CAND(key_, j_)                                  \
  if ((key_) < dl[KNN - 1]) {                                  \
    float _k = (key_); int _j = (j_);                          \
    _Pragma("unroll")                                          \
    for (int p = 0; p < KNN; ++p) {                            \
      bool sw = _k < dl[p];                                    \
      float od = dl[p]; int oi = il[p];                        \
      dl[p] = sw ? _k : od; il[p] = sw ? _j : oi;              \
      _k = sw ? od : _k; _j = sw ? oi : _j;                    \
    }                                                          \
  }

// ---------------------------------------------------------------- kNN v7 = v3 + LDS fixes only
// 32 rows x 64 cands/chunk, 8 select lanes/row, exact lex (d,idx) semantics,
// in-LDS 8-way merge (one thread/row), global 4-way merge. vs v3:
// (a) merge buffer: d=f32 + idx=u16, p-major XOR layout
//     elem(p,g,r)=p*256+g*32+(r^4g) -> 30KB LDS total (was 40KB) = 5 blk/CU,
//     merge reads conflict-FREE (v3's stride-20 reads were 32-way), dumps 2-way.
// (b) dist tile col-swizzled by (row&1)<<4 (write conflicts 4->2-way, v5-measured).
// Plain __launch_bounds__(256): v3's 64-VGPR compile config, untouched.
template <int C, int CSPLIT>
__global__ __launch_bounds__(256) void knn7_kernel(const float* __restrict__ X, int lda,
                                                   const float* __restrict__ sq,
                                                   float* __restrict__ pd, int* __restrict__ pi) {
  constexpr int ROWS = 32, CHK = 64, KB = 32, SEL = 8;
  constexpr int KP = KB + 4;                  // staging stride (f4-aligned, padded)
  constexpr int DP = CHK + 1;                 // 65: dist stride
  constexpr int NKB = (C == 3) ? 1 : C / KB;
  constexpr int XI_W = (C == 3) ? 4 : KP;
  constexpr int LAYOUT = ROWS * XI_W + CHK * XI_W + ROWS * DP;   // <= 5536
  constexpr int MBUF = KNN * 256 + (KNN * 256) / 2;              // f32 + u16 = 7680
  constexpr int SMF = (LAYOUT > MBUF) ? LAYOUT : MBUF;
  __shared__ __align__(16) float smem[SMF];
  float* xi = smem;                                    // [ROWS][XI_W]
  float* xj = smem + ROWS * XI_W;                      // [CHK][XI_W]
  float* dist = smem + (ROWS + CHK) * XI_W;            // [ROWS][DP] (col-swizzled)
  float* mbd = smem;                                   // [KNN][256] p-major (aliased)
  unsigned short* mbi = (unsigned short*)(smem + KNN * 256);

  const int b = blockIdx.z;
  const int m0 = blockIdx.x * ROWS;
  const int jsplit = blockIdx.y * (NPTS / CSPLIT);
  const int t = threadIdx.x;
  const int tx = t & 15, ty = t >> 4;         // compute roles: rows ty+16i, cols tx+16j
  const int sr = t >> 3, ss = t & 7;          // select roles: row sr, col-slice ss
  const float* Xb = X + (size_t)b * NPTS * lda;
  const float* sqb = sq + b * NPTS;

  float dl[KNN]; int il[KNN];
#pragma unroll
  for (int p = 0; p < KNN; ++p) { dl[p] = INFINITY; il[p] = 0x7fffffff; }

  for (int c0 = 0; c0 < NPTS / CSPLIT; c0 += CHK) {
    const int jb = jsplit + c0;
    float acc[2][4] = {};

    if constexpr (C == 3) {
      __syncthreads();
      // full-coverage grid-stride staging (96 + 192 elements, 256 threads)
      for (int e = t; e < ROWS * 3; e += 256) {
        int rr = e / 3, cc = e % 3;
        xi[rr * 4 + cc] = Xb[(size_t)(m0 + rr) * lda + cc];
      }
      for (int e = t; e < CHK * 3; e += 256) {
        int rr = e / 3, cc = e % 3;
        xj[rr * 4 + cc] = Xb[(size_t)(jb + rr) * lda + cc];
      }
      __syncthreads();
#pragma unroll
      for (int i = 0; i < 2; ++i) {
        const float* xr = xi + (ty + 16 * i) * 4;
        float x0 = xr[0], x1 = xr[1], x2 = xr[2];
#pragma unroll
        for (int j = 0; j < 4; ++j) {
          const float* xc = xj + (tx + 16 * j) * 4;
          acc[i][j] = fmaf(x0, xc[0], fmaf(x1, xc[1], x2 * xc[2]));
        }
      }
    } else {
#pragma unroll
      for (int kb = 0; kb < NKB; ++kb) {
        __syncthreads();
        // stage xi 32x32 (256 f4) + xj 64x32 (512 f4): 3 f4 per thread
#pragma unroll
        for (int q = 0; q < 3; ++q) {
          if (q == 0) {
            int rr = t >> 3, cc = t & 7;
            *(float4*)(xi + rr * KP + cc * 4) =
                *(const float4*)(Xb + (size_t)(m0 + rr) * lda + kb * KB + cc * 4);
          } else {
            int f = t + (q - 1) * 256;
            int rr = f >> 3, cc = f & 7;
            *(float4*)(xj + rr * KP + cc * 4) =
                *(const float4*)(Xb + (size_t)(jb + rr) * lda + kb * KB + cc * 4);
          }
        }
        __syncthreads();
#pragma unroll
        for (int k4 = 0; k4 < KB / 4; ++k4) {
          float4 av[2], bv[4];
#pragma unroll
          for (int i = 0; i < 2; ++i) av[i] = *(const float4*)(xi + (ty + 16 * i) * KP + k4 * 4);
#pragma unroll
          for (int j = 0; j < 4; ++j) bv[j] = *(const float4*)(xj + (tx + 16 * j) * KP + k4 * 4);
#pragma unroll
          for (int i = 0; i < 2; ++i)
#pragma unroll
            for (int j = 0; j < 4; ++j) {
              acc[i][j] = fmaf(av[i].x, bv[j].x, acc[i][j]);
              acc[i][j] = fmaf(av[i].y, bv[j].y, acc[i][j]);
              acc[i][j] = fmaf(av[i].z, bv[j].z, acc[i][j]);
              acc[i][j] = fmaf(av[i].w, bv[j].w, acc[i][j]);
            }
        }
      }
    }

    // ranking key: sq_j - 2*dot (same fma order as v3 -> bit-identical keys).
    // dist col swizzled: col' = col ^ ((row&1)<<4)
    float sqv[4];
#pragma unroll
    for (int j = 0; j < 4; ++j) sqv[j] = sqb[jb + tx + 16 * j];
#pragma unroll
    for (int i = 0; i < 2; ++i) {
      const int row = ty + 16 * i;
      const int sw = (row & 1) << 4;
#pragma unroll
      for (int j = 0; j < 4; ++j)
        dist[row * DP + ((tx + 16 * j) ^ sw)] = fmaf(-2.f, acc[i][j], sqv[j]);
    }
    __syncthreads();

    // select: 8 lanes/row, each scans 8 cands (ascending j within lane)
    {
      const int sw = (sr & 1) << 4;
#pragma unroll
      for (int q = 0; q < 8; ++q) {
        float key = dist[sr * DP + ((ss * 8 + q) ^ sw)];
        int jidx = jb + ss * 8 + q;
        INSERT_CAND(key, jidx)
      }
    }
  }

  // dump per-lane lists to LDS: elem(p,g,r) = p*256 + g*32 + (r ^ 4g)
  __syncthreads();
  {
    const int slot = ss * 32 + (sr ^ (ss * 4));
#pragma unroll
    for (int p = 0; p < KNN; ++p) {
      mbd[p * 256 + slot] = dl[p];
      mbi[p * 256 + slot] = (unsigned short)(il[p] & 0xFFFF);  // sentinel -> 0xFFFF (d=INF)
    }
  }
  __syncthreads();

  // in-kernel exact 8-way lex merge: one thread per row
  if (t < ROWS) {
    int p[SEL];
#pragma unroll
    for (int g = 0; g < SEL; ++g) p[g] = 0;
    const size_t base = ((size_t)(b * NPTS + m0 + t) * CSPLIT + blockIdx.y) * KNN;
    for (int k = 0; k < KNN; ++k) {
      float bd = INFINITY; int bi = 0x7fffffff; int bg = 0;
#pragma unroll
      for (int g = 0; g < SEL; ++g) {
        const int slot = g * 32 + (t ^ (g * 4));
        float dd = mbd[p[g] * 256 + slot];
        int iv = (int)mbi[p[g] * 256 + slot];
        if (dd < bd || (dd == bd && iv < bi)) { bd = dd; bi = iv; bg = g; }
      }
      pd[base + k] = bd;
      pi[base + k] = bi;
#pragma unroll
      for (int g = 0; g < SEL; ++g) p[g] += (bg == g) ? 1 : 0;
    }
  }
}

// ---------------------------------------------------------------- exact NL-way merge of sorted lists
template <int NL>
__global__ __launch_bounds__(256) void knnmerge_kernel(const float* __restrict__ pd,
                                                       const int* __restrict__ pi,
                                                       int* __restrict__ knn_out) {
  int row = blockIdx.x * 256 + threadIdx.x;
  if (row >= M_TOT) return;
  const float* d = pd + (size_t)row * NL * KNN;
  const int* ii = pi + (size_t)row * NL * KNN;
  int p[NL];
#pragma unroll
  for (int g = 0; g < NL; ++g) p[g] = 0;
  int* orow = knn_out + (size_t)row * KNN;
  for (int k = 0; k < KNN; ++k) {
    float bd = INFINITY; int bi = 0x7fffffff; int bg = 0;
#pragma unroll
    for (int g = 0; g < NL; ++g) {
      float dd = d[g * KNN + p[g]];
      int iv = ii[g * KNN + p[g]];
      if (dd < bd || (dd == bd && iv < bi)) { bd = dd; bi = iv; bg = g; }
    }
    orow[k] = bi;
#pragma unroll
    for (int g = 0; g < NL; ++g) p[g] += (bg == g) ? 1 : 0;   // static-index update
  }
}

// ---------------------------------------------------------------- weight prep: [Wd ; Wc-Wd]
__global__ __launch_bounds__(256) void wcat_kernel(const float* __restrict__ W, int O, int Cc,
                                                   float* __restrict__ out) {
  int i = blockIdx.x * 256 + threadIdx.x;
  if (i >= O * Cc) return;
  int o = i / Cc, c = i % Cc;
  float wd = W[(size_t)o * 2 * Cc + c];
  float wc = W[(size_t)o * 2 * Cc + Cc + c];
  out[(size_t)o * Cc + c] = wd;              // rows 0..O-1   : v = Wd * x
  out[(size_t)(O + o) * Cc + c] = wc - wd;   // rows O..2O-1  : u = (Wc-Wd) * x
}

// ---------------------------------------------------------------- fp32 tiled GEMM
// out[M, NO] = A[M, K](lda) @ Wt[NO, K]^T ;  BM=BN=64, BK=16, 256 thr, 4x4 micro-tile
template <bool FUSE>
__global__ __launch_bounds__(256) void gemm_kernel(const float* __restrict__ A, int lda, int K,
                                                   const float* __restrict__ Wt, int NO,
                                                   float* __restrict__ out,
                                                   const float* __restrict__ bn) {
  __shared__ float As[16][68];
  __shared__ float Bs[16][68];
  const int t = threadIdx.x;
  const int tx = t & 15, ty = t >> 4;
  const int m0 = blockIdx.x * 64, n0 = blockIdx.y * 64;
  float acc[4][4] = {};

  for (int k0 = 0; k0 < K; k0 += 16) {
#pragma unroll
    for (int q = 0; q < 4; ++q) {
      int e = t + q * 256;
      int rr = e >> 4, cc = e & 15;
      int kk = k0 + cc;
      As[cc][rr] = (kk < K) ? A[(size_t)(m0 + rr) * lda + kk] : 0.f;
      Bs[cc][rr] = (kk < K) ? Wt[(size_t)(n0 + rr) * K + kk] : 0.f;
    }
    __syncthreads();
#pragma unroll
    for (int kk = 0; kk < 16; ++kk) {
      float4 av = *(const float4*)(&As[kk][ty * 4]);
      float4 bv = *(const float4*)(&Bs[kk][tx * 4]);
      float a[4] = {av.x, av.y, av.z, av.w};
      float bb[4] = {bv.x, bv.y, bv.z, bv.w};
#pragma unroll
      for (int i = 0; i < 4; ++i)
#pragma unroll
        for (int j = 0; j < 4; ++j) acc[i][j] = fmaf(a[i], bb[j], acc[i][j]);
    }
    __syncthreads();
  }

#pragma unroll
  for (int i = 0; i < 4; ++i) {
    int row = m0 + ty * 4 + i;
#pragma unroll
    for (int j = 0; j < 4; ++j) {
      int col = n0 + tx * 4 + j;
      float v = acc[i][j];
      if constexpr (FUSE) {
        float g = bn[col], be = bn[NO + col], mm = bn[2 * NO + col], va = bn[3 * NO + col];
        float s = g * rsqrtf(va + 1e-5f);
        v = fmaf(s, v - mm, be);
        v = v > 0.f ? v : 0.2f * v;
      }
      out[(size_t)row * NO + col] = v;
    }
  }
}

// ---------------------------------------------------------------- gather + k-max + BN + lrelu
__global__ void gathermax_kernel(const float* __restrict__ uv, const int* __restrict__ knn_in,
                                 const float* __restrict__ bn, int O,
                                 float* __restrict__ outc, int ldo) {
  const int n = blockIdx.x;   // global row b*N + n
  const int o = threadIdx.x;
  __shared__ int js[KNN];
  if (o < KNN) js[o] = knn_in[(size_t)n * KNN + o];
  __syncthreads();
  const int b = n >> 11;
  const int ld2 = 2 * O;
  const float* uvb = uv + (size_t)b * NPTS * ld2;
  float m = -INFINITY;
#pragma unroll
  for (int k = 0; k < KNN; ++k) m = fmaxf(m, uvb[(size_t)js[k] * ld2 + o]);
  float u = uv[(size_t)n * ld2 + O + o];
  float g = bn[o], be = bn[O + o], mm = bn[2 * O + o], va = bn[3 * O + o];
  float s = g * rsqrtf(va + 1e-5f);
  float y = fmaf(s, m + u - mm, be);
  y = y > 0.f ? y : 0.2f * y;
  outc[(size_t)n * ldo + o] = y;
}

// ---------------------------------------------------------------- final global max+avg reduce
__global__ __launch_bounds__(256) void reduce1_kernel(const float* __restrict__ feat,
                                                      float* __restrict__ part) {
  const int sp = blockIdx.x;                 // 16 splits of 128 rows
  const int b = blockIdx.z;
  const int o = blockIdx.y * 256 + threadIdx.x;
  const float* f = feat + ((size_t)b * NPTS + sp * 128) * 1024 + o;
  float mx = -INFINITY, sm = 0.f;
  for (int n = 0; n < 128; ++n) { float v = f[(size_t)n * 1024]; mx = fmaxf(mx, v); sm += v; }
  part[((size_t)(b * 16 + sp)) * 1024 + o] = mx;
  part[131072 + ((size_t)(b * 16 + sp)) * 1024 + o] = sm;
}

__global__ __launch_bounds__(256) void reduce2_kernel(const float* __restrict__ part,
                                                      float* __restrict__ out) {
  const int b = blockIdx.y;
  const int o = blockIdx.x * 256 + threadIdx.x;
  float mx = -INFINITY, sm = 0.f;
  for (int sp = 0; sp < 16; ++sp) {
    mx = fmaxf(mx, part[((size_t)(b * 16 + sp)) * 1024 + o]);
    sm += part[131072 + ((size_t)(b * 16 + sp)) * 1024 + o];
  }
  out[(size_t)b * 2048 + o] = mx;
  out[(size_t)b * 2048 + 1024 + o] = sm * (1.f / 2048.f);
}

// ---------------------------------------------------------------- launch
extern "C" void kernel_launch(void* const* d_in, const int* in_sizes, int n_in,
                              void* d_out, int out_size, void* d_ws, size_t ws_size,
                              hipStream_t stream) {
  const float* x   = (const float*)d_in[0];
  const float* W1  = (const float*)d_in[1];
  const float* W2  = (const float*)d_in[2];
  const float* W3  = (const float*)d_in[3];
  const float* W4  = (const float*)d_in[4];
  const float* W5  = (const float*)d_in[5];
  const float* bn1 = (const float*)d_in[6];
  const float* bn2 = (const float*)d_in[7];
  const float* bn3 = (const float*)d_in[8];
  const float* bn4 = (const float*)d_in[9];
  const float* bn5 = (const float*)d_in[10];
  float* out = (float*)d_out;

  char* ws = (char*)d_ws;
  float* xcat  = (float*)(ws);                 // 16384*512 f32 = 32 MiB
  float* uv    = (float*)(ws + 33554432);      // 16384*1024 f32 = 64 MiB (uv / feat)
  int*   knnb  = (int*)  (ws + 100663296);     // 16384*20 int  = 1.25 MiB
  float* sqb   = (float*)(ws + 101974016);     // 16384 f32
  float* wcat  = (float*)(ws + 102039552);     // <= 512*256 f32
  float* part  = (float*)(ws + 102563840);     // 2*8*16*1024 f32 = 1 MiB
  // kNN partial lists alias the (idle during kNN) uv region: 2 x 5.25 MiB
  float* pd    = uv;
  int*   pi    = (int*)(ws + 33554432 + 22020096);

  const dim3 kg(NPTS / 32, 4, NBAT);   // 2048 blocks

  // ---- Layer 1: x(B,N,3) -> x1(64) @ xcat col 0
  sqnorm_kernel<<<64, 256, 0, stream>>>(x, 3, 3, sqb);
  knn7_kernel<3, 4><<<kg, 256, 0, stream>>>(x, 3, sqb, pd, pi);
  knnmerge_kernel<4><<<64, 256, 0, stream>>>(pd, pi, knnb);
  wcat_kernel<<<1, 256, 0, stream>>>(W1, 64, 3, wcat);
  gemm_kernel<false><<<dim3(256, 2), 256, 0, stream>>>(x, 3, 3, wcat, 128, uv, nullptr);
  gathermax_kernel<<<16384, 64, 0, stream>>>(uv, knnb, bn1, 64, xcat + 0, 512);

  // ---- Layer 2: x1(64) -> x2(64) @ xcat col 64
  sqnorm_kernel<<<64, 256, 0, stream>>>(xcat, 512, 64, sqb);
  knn7_kernel<64, 4><<<kg, 256, 0, stream>>>(xcat, 512, sqb, pd, pi);
  knnmerge_kernel<4><<<64, 256, 0, stream>>>(pd, pi, knnb);
  wcat_kernel<<<16, 256, 0, stream>>>(W2, 64, 64, wcat);
  gemm_kernel<false><<<dim3(256, 2), 256, 0, stream>>>(xcat, 512, 64, wcat, 128, uv, nullptr);
  gathermax_kernel<<<16384, 64, 0, stream>>>(uv, knnb, bn2, 64, xcat + 64, 512);

  // ---- Layer 3: x2(64) -> x3(128) @ xcat col 128
  sqnorm_kernel<<<64, 256, 0, stream>>>(xcat + 64, 512, 64, sqb);
  knn7_kernel<64, 4><<<kg, 256, 0, stream>>>(xcat + 64, 512, sqb, pd, pi);
  knnmerge_kernel<4><<<64, 256, 0, stream>>>(pd, pi, knnb);
  wcat_kernel<<<32, 256, 0, stream>>>(W3, 128, 64, wcat);
  gemm_kernel<false><<<dim3(256, 4), 256, 0, stream>>>(xcat + 64, 512, 64, wcat, 256, uv, nullptr);
  gathermax_kernel<<<16384, 128, 0, stream>>>(uv, knnb, bn3, 128, xcat + 128, 512);

  // ---- Layer 4: x3(128) -> x4(256) @ xcat col 256
  sqnorm_kernel<<<64, 256, 0, stream>>>(xcat + 128, 512, 128, sqb);
  knn7_kernel<128, 4><<<kg, 256, 0, stream>>>(xcat + 128, 512, sqb, pd, pi);
  knnmerge_kernel<4><<<64, 256, 0, stream>>>(pd, pi, knnb);
  wcat_kernel<<<128, 256, 0, stream>>>(W4, 256, 128, wcat);
  gemm_kernel<false><<<dim3(256, 8), 256, 0, stream>>>(xcat + 128, 512, 128, wcat, 512, uv, nullptr);
  gathermax_kernel<<<16384, 256, 0, stream>>>(uv, knnb, bn4, 256, xcat + 256, 512);

  // ---- Final MLP: feat = lrelu(bn5(xcat @ W5^T))
  gemm_kernel<true><<<dim3(256, 16), 256, 0, stream>>>(xcat, 512, 512, W5, 1024, uv, bn5);

  // ---- global max + mean over N
  reduce1_kernel<<<dim3(16, 4, 8), 256, 0, stream>>>(uv, part);
  reduce2_kernel<<<dim3(4, 8), 256, 0, stream>>>(part, out);

  (void)in_sizes; (void)n_in; (void)out_size; (void)ws_size;
}